// Round 1
// 183.460 us; speedup vs baseline: 1.0351x; 1.0351x over previous
//
#include <hip/hip_runtime.h>
#include <hip/hip_bf16.h>

#define EMBED 128
#define HEADS 16
#define NEG 0.2f

typedef __attribute__((ext_vector_type(8))) short short8;
typedef __attribute__((ext_vector_type(4))) float floatx4;

static __device__ __forceinline__ float leaky(float x) { return x > 0.f ? x : NEG * x; }

static __device__ __forceinline__ short f2bf_bits(float f) {
  __hip_bfloat16 h = __float2bfloat16(f);
  union { __hip_bfloat16 b; short s; } u;
  u.b = h;
  return u.s;
}

// ---------------- CSR build ----------------

__global__ void k_hist(const int* __restrict__ ei, int E, int N, int* __restrict__ deg) {
  int i = blockIdx.x * blockDim.x + threadIdx.x;
  int Et = E + N;
  if (i >= Et) return;
  int d = (i < E) ? ei[E + i] : (i - E);
  atomicAdd(&deg[d], 1);
}

// single-block shuffle scan over deg -> row_ptr/cursor (replaces scan1+scan2+scan3)
__global__ __launch_bounds__(1024) void k_scan(const int* __restrict__ deg,
                                               int* __restrict__ row_ptr,
                                               int* __restrict__ cursor, int N) {
  __shared__ int wsum[16];
  int tid = threadIdx.x;
  int lane = tid & 63, w = tid >> 6;
  int base = 0;
  for (int c0 = 0; c0 < N; c0 += 1024) {
    int i = c0 + tid;
    int v = (i < N) ? deg[i] : 0;
    int s = v;
#pragma unroll
    for (int dd = 1; dd < 64; dd <<= 1) {
      int t = __shfl_up(s, dd);
      if (lane >= dd) s += t;
    }
    if (lane == 63) wsum[w] = s;
    __syncthreads();
    int carry = 0, ctot = 0;
#pragma unroll
    for (int k = 0; k < 16; ++k) {
      int t = wsum[k];
      ctot += t;
      if (k < w) carry += t;
    }
    int excl = base + carry + s - v;
    if (i < N) {
      row_ptr[i] = excl;
      cursor[i] = excl;
    }
    base += ctot;
    __syncthreads();
  }
  if (tid == 0) row_ptr[N] = base;
}

__global__ void k_scatter(const int* __restrict__ ei, int E, int N,
                          int* __restrict__ cursor, int* __restrict__ csr_src) {
  int i = blockIdx.x * blockDim.x + threadIdx.x;
  int Et = E + N;
  if (i >= Et) return;
  int s = (i < E) ? ei[i] : (i - E);
  int d = (i < E) ? ei[E + i] : (i - E);
  int pos = atomicAdd(&cursor[d], 1);
  csr_src[pos] = s;
}

// ---------------- merged prep: W1^T transpose (blocks 0..63) + w~/u vectors + zeroing ----------------

__global__ __launch_bounds__(256) void k_prep(const float* __restrict__ W1,
                                              const float* __restrict__ a_src1,
                                              const float* __restrict__ a_dst1,
                                              const float* __restrict__ W2,
                                              const float* __restrict__ a_src2,
                                              const float* __restrict__ a_dst2,
                                              const float* __restrict__ Wc,
                                              const float* __restrict__ b2,
                                              const float* __restrict__ bc,
                                              float* __restrict__ wsAll,
                                              float* __restrict__ uvec,
                                              float* __restrict__ cconst,
                                              short* __restrict__ hi,
                                              short* __restrict__ lo,
                                              float* __restrict__ part,
                                              int* __restrict__ deg,
                                              int N) {
  __shared__ float tile[64][65];
  if (blockIdx.x < 64) {
    // W1^T hi/lo bf16 via LDS tile transpose: layout [h][j][c]
    int b = blockIdx.x;
    int h = b & 15;
    int c0 = ((b >> 4) & 1) * 64;
    int j0 = ((b >> 5) & 1) * 64;
    int t = threadIdx.x;
#pragma unroll
    for (int i = 0; i < 4; ++i) {
      int idx4 = i * 256 + t;
      int c = idx4 >> 4, j4 = idx4 & 15;
      float4 v = *(const float4*)&W1[(size_t)(c0 + c) * 2048 + h * 128 + j0 + j4 * 4];
      tile[c][j4 * 4 + 0] = v.x;
      tile[c][j4 * 4 + 1] = v.y;
      tile[c][j4 * 4 + 2] = v.z;
      tile[c][j4 * 4 + 3] = v.w;
    }
    __syncthreads();
#pragma unroll
    for (int i = 0; i < 4; ++i) {
      int idx = i * 256 + t;
      int j = idx >> 4, c4 = idx & 15;
      unsigned short vh[4], vl[4];
#pragma unroll
      for (int ii = 0; ii < 4; ++ii) {
        float wv = tile[c4 * 4 + ii][j];
        short hb = f2bf_bits(wv);
        float hf = __uint_as_float(((unsigned int)(unsigned short)hb) << 16);
        vh[ii] = (unsigned short)hb;
        vl[ii] = (unsigned short)f2bf_bits(wv - hf);
      }
      size_t o = (size_t)h * 16384 + (size_t)(j0 + j) * 128 + c0 + c4 * 4;
      *(ushort4*)&hi[o] = make_ushort4(vh[0], vh[1], vh[2], vh[3]);
      *(ushort4*)&lo[o] = make_ushort4(vl[0], vl[1], vl[2], vl[3]);
    }
    return;
  }
  int gid = (blockIdx.x - 64) * 256 + threadIdx.x;
  if (gid < 4096) {
    int sel = gid >> 11;
    int id = gid & 2047;
    int h = id >> 7, k = id & 127;
    const float* av = sel ? a_dst1 : a_src1;
    float sum = 0.f;
    const float* wrow = W1 + (size_t)k * 2048 + h * 128;
    const float* arow = av + h * 128;
#pragma unroll 4
    for (int c = 0; c < 128; ++c) sum += wrow[c] * arow[c];
    wsAll[gid] = sum;
  } else if (gid < 10240) {
    int g = gid - 4096;
    int sel = g >> 11;  // 0: Wc, 1: a_src2, 2: a_dst2
    int k = g & 2047;
    const float* v = sel == 0 ? Wc : (sel == 1 ? a_src2 : a_dst2);
    const float* wrow = W2 + (size_t)k * 128;
    float s = 0.f;
#pragma unroll 4
    for (int j = 0; j < 128; ++j) s += wrow[j] * v[j];
    uvec[g] = s;
  } else if (gid == 10240) {
    float s = 0.f;
    for (int j = 0; j < 128; ++j) s += b2[j] * Wc[j];
    *cconst = s + bc[0];
  } else if (gid >= 10496) {
    int z = gid - 10496;
    if (z < 3 * N) part[z] = 0.f;
    else if (z < 4 * N) deg[z - 3 * N] = 0;
  }
}

// ---------------- layer-1 logits: thread per (n,h); weights [c][h] in LDS ----------------

__global__ __launch_bounds__(256) void k_al1v2(const float* __restrict__ x,
                                               const float* __restrict__ wsAll,
                                               float* __restrict__ als,
                                               float* __restrict__ ald, int N) {
  __shared__ float wss[128][16], wsd[128][16];
  int tid = threadIdx.x;
  for (int i = tid; i < 2048; i += 256) {
    int h = i >> 7, c = i & 127;
    wss[c][h] = wsAll[i];
    wsd[c][h] = wsAll[2048 + i];
  }
  __syncthreads();
  int gid = blockIdx.x * 256 + tid;
  int n = gid >> 4, h = gid & 15;
  if (n >= N) return;
  const float4* xp = (const float4*)(x + (size_t)n * 128);
  float ps = 0.f, pd = 0.f;
#pragma unroll 8
  for (int c4 = 0; c4 < 32; ++c4) {
    float4 xv = xp[c4];
    int c = c4 * 4;
    ps += xv.x * wss[c][h] + xv.y * wss[c + 1][h] + xv.z * wss[c + 2][h] + xv.w * wss[c + 3][h];
    pd += xv.x * wsd[c][h] + xv.y * wsd[c + 1][h] + xv.z * wsd[c + 2][h] + xv.w * wsd[c + 3][h];
  }
  als[gid] = ps;
  ald[gid] = pd;
}

// ---------------- layer-1 attention: staged CSR in regs + depth-2 software pipeline ----------------

__global__ __launch_bounds__(256) void k_attn1h(const float* __restrict__ x,
                                                const float* __restrict__ als,
                                                const float* __restrict__ ald,
                                                const int* __restrict__ row_ptr,
                                                const int* __restrict__ csr,
                                                __hip_bfloat16* __restrict__ xaggb,
                                                int N) {
  __shared__ float accsh[2][64][37];  // 32 acc + 4 z per lane

  int tid = threadIdx.x;
  int w = tid >> 6, lane = tid & 63;
  int slot = w >> 1, half = w & 1;
  int d = blockIdx.x * 2 + slot;
  bool active = d < N;

  int e0 = 0, deg = 0;
  if (active) {
    e0 = row_ptr[d];
    deg = row_ptr[d + 1] - e0;
  }

  int g = lane >> 4, c8 = lane & 15;
  float4 aldh4 = make_float4(0.f, 0.f, 0.f, 0.f);
  if (active) aldh4 = *(const float4*)&ald[(size_t)d * 16 + g * 4];

  float acc[4][8];
  float zacc[4] = {0.f, 0.f, 0.f, 0.f};
#pragma unroll
  for (int hh = 0; hh < 4; ++hh)
#pragma unroll
    for (int i = 0; i < 8; ++i) acc[hh][i] = 0.f;

  if (active) {
    // stage up to 64 CSR indices in a lane register (1 load), read via shuffle
    int sreg = 0;
    if (lane < deg) sreg = csr[e0 + lane];
    const float* xc = x + c8 * 8;

    int e = half;
    bool have = e < deg;
    int sC = 0;
    float4 alC = make_float4(0.f, 0.f, 0.f, 0.f);
    float4 xaC = alC, xbC = alC;
    if (have) {
      sC = (e < 64) ? __shfl(sreg, e) : csr[e0 + e];
      alC = *(const float4*)&als[(size_t)sC * 16 + g * 4];
      const float4* xp = (const float4*)(xc + (size_t)sC * 128);
      xaC = xp[0];
      xbC = xp[1];
    }
    while (have) {
      int e2 = e + 2;
      bool have2 = e2 < deg;
      int sN = 0;
      float4 alN = alC, xaN = xaC, xbN = xbC;
      if (have2) {
        sN = (e2 < 64) ? __shfl(sreg, e2) : csr[e0 + e2];
        alN = *(const float4*)&als[(size_t)sN * 16 + g * 4];
        const float4* xp2 = (const float4*)(xc + (size_t)sN * 128);
        xaN = xp2[0];
        xbN = xp2[1];
      }
      float ev0 = __expf(leaky(alC.x + aldh4.x));
      float ev1 = __expf(leaky(alC.y + aldh4.y));
      float ev2 = __expf(leaky(alC.z + aldh4.z));
      float ev3 = __expf(leaky(alC.w + aldh4.w));
      zacc[0] += ev0; zacc[1] += ev1; zacc[2] += ev2; zacc[3] += ev3;
      acc[0][0] += ev0 * xaC.x; acc[0][1] += ev0 * xaC.y; acc[0][2] += ev0 * xaC.z; acc[0][3] += ev0 * xaC.w;
      acc[0][4] += ev0 * xbC.x; acc[0][5] += ev0 * xbC.y; acc[0][6] += ev0 * xbC.z; acc[0][7] += ev0 * xbC.w;
      acc[1][0] += ev1 * xaC.x; acc[1][1] += ev1 * xaC.y; acc[1][2] += ev1 * xaC.z; acc[1][3] += ev1 * xaC.w;
      acc[1][4] += ev1 * xbC.x; acc[1][5] += ev1 * xbC.y; acc[1][6] += ev1 * xbC.z; acc[1][7] += ev1 * xbC.w;
      acc[2][0] += ev2 * xaC.x; acc[2][1] += ev2 * xaC.y; acc[2][2] += ev2 * xaC.z; acc[2][3] += ev2 * xaC.w;
      acc[2][4] += ev2 * xbC.x; acc[2][5] += ev2 * xbC.y; acc[2][6] += ev2 * xbC.z; acc[2][7] += ev2 * xbC.w;
      acc[3][0] += ev3 * xaC.x; acc[3][1] += ev3 * xaC.y; acc[3][2] += ev3 * xaC.z; acc[3][3] += ev3 * xaC.w;
      acc[3][4] += ev3 * xbC.x; acc[3][5] += ev3 * xbC.y; acc[3][6] += ev3 * xbC.z; acc[3][7] += ev3 * xbC.w;
      e = e2;
      have = have2;
      sC = sN;
      alC = alN;
      xaC = xaN;
      xbC = xbN;
    }
  }

  // combine halves through LDS (32 acc + 4 z per lane)
  if (half == 1) {
#pragma unroll
    for (int hh = 0; hh < 4; ++hh) {
#pragma unroll
      for (int i = 0; i < 8; ++i)
        accsh[slot][lane][hh * 8 + i] = acc[hh][i];
      accsh[slot][lane][32 + hh] = zacc[hh];
    }
  }
  __syncthreads();
  if (half == 0 && active) {
#pragma unroll
    for (int hh = 0; hh < 4; ++hh) {
      int h = g * 4 + hh;
      float z = zacc[hh] + accsh[slot][lane][32 + hh];
      float iz = 1.f / (z + 1e-16f);
      __hip_bfloat16 t[8];
#pragma unroll
      for (int i = 0; i < 8; ++i) {
        float v = (acc[hh][i] + accsh[slot][lane][hh * 8 + i]) * iz;
        t[i] = __float2bfloat16(v);
      }
      *(uint4*)(xaggb + (size_t)h * N * 128 + (size_t)d * 128 + c8 * 8) = *(uint4*)t;
    }
  }
}

// ---------------- fused: Bh+Bl in LDS, atomic accumulation into part (k_redparts eliminated) ----------------

__global__ __launch_bounds__(256, 2) void k_fused(const __hip_bfloat16* __restrict__ xaggb,
                                                  const short* __restrict__ w1t_hi,
                                                  const short* __restrict__ w1t_lo,
                                                  const float* __restrict__ b1,
                                                  const float* __restrict__ uvec,
                                                  float* __restrict__ partc,
                                                  float* __restrict__ parts,
                                                  float* __restrict__ partd,
                                                  int N) {
  __shared__ float sh[512];
  __shared__ __align__(16) char Bh[32768];
  __shared__ __align__(16) char Bl[32768];
  int tid = threadIdx.x;
  int h = blockIdx.y;
  int n0 = blockIdx.x * 256;

  for (int i = tid; i < 512; i += 256) {
    int arr = i >> 7, jj = i & 127;
    sh[i] = (arr == 0) ? b1[h * 128 + jj] : uvec[(arr - 1) * 2048 + h * 128 + jj];
  }
  const char* gbh = (const char*)(w1t_hi + (size_t)h * 16384);
  const char* gbl = (const char*)(w1t_lo + (size_t)h * 16384);
#pragma unroll
  for (int i = 0; i < 8; ++i) {
    int ci = i * 256 + tid;
    int row = ci >> 4, kc = ci & 15;
    int po = row * 256 + ((kc ^ (row & 15)) << 4);
    *(uint4*)(Bh + po) = *(const uint4*)(gbh + ci * 16);
    *(uint4*)(Bl + po) = *(const uint4*)(gbl + ci * 16);
  }

  int w = tid >> 6, lane = tid & 63;
  int quad = lane >> 4, l15 = lane & 15;
  int nw = n0 + w * 64;

  const char* abase = (const char*)xaggb + (size_t)h * N * 256;
  short8 a[4][4];
#pragma unroll
  for (int nt = 0; nt < 4; ++nt) {
    int node = nw + nt * 16 + l15;
    if (node >= N) node = N - 1;
    const char* rowp = abase + (size_t)node * 256 + quad * 16;
#pragma unroll
    for (int ks = 0; ks < 4; ++ks)
      a[nt][ks] = *(const short8*)(rowp + ks * 64);
  }
  __syncthreads();

  floatx4 acc[4][8];
#pragma unroll
  for (int jt = 0; jt < 8; ++jt) {
    floatx4 bb = *(const floatx4*)&sh[jt * 16 + quad * 4];
#pragma unroll
    for (int nt = 0; nt < 4; ++nt) acc[nt][jt] = bb;
  }

  for (int ks = 0; ks < 4; ++ks) {
    int xo = (((ks * 4 + quad) ^ l15) << 4);
#pragma unroll
    for (int jt = 0; jt < 8; ++jt) {
      int po = (jt * 16 + l15) * 256 + xo;
      short8 wh = *(const short8*)(Bh + po);
      short8 wl = *(const short8*)(Bl + po);
#pragma unroll
      for (int nt = 0; nt < 4; ++nt) {
        acc[nt][jt] = __builtin_amdgcn_mfma_f32_16x16x32_bf16(wh, a[nt][ks], acc[nt][jt], 0, 0, 0);
        acc[nt][jt] = __builtin_amdgcn_mfma_f32_16x16x32_bf16(wl, a[nt][ks], acc[nt][jt], 0, 0, 0);
      }
    }
  }

  float pc[4] = {0.f, 0.f, 0.f, 0.f};
  float ps[4] = {0.f, 0.f, 0.f, 0.f};
  float pd[4] = {0.f, 0.f, 0.f, 0.f};
#pragma unroll
  for (int jt = 0; jt < 8; ++jt) {
    floatx4 uc = *(const floatx4*)&sh[128 + jt * 16 + quad * 4];
    floatx4 us = *(const floatx4*)&sh[256 + jt * 16 + quad * 4];
    floatx4 ud = *(const floatx4*)&sh[384 + jt * 16 + quad * 4];
#pragma unroll
    for (int nt = 0; nt < 4; ++nt) {
#pragma unroll
      for (int r = 0; r < 4; ++r) {
        float v = acc[nt][jt][r];
        float e = v > 0.f ? v : (__expf(v) - 1.f);
        pc[nt] += e * uc[r];
        ps[nt] += e * us[r];
        pd[nt] += e * ud[r];
      }
    }
  }
#pragma unroll
  for (int nt = 0; nt < 4; ++nt) {
    float c = pc[nt], s = ps[nt], dd = pd[nt];
    c += __shfl_xor(c, 16); c += __shfl_xor(c, 32);
    s += __shfl_xor(s, 16); s += __shfl_xor(s, 32);
    dd += __shfl_xor(dd, 16); dd += __shfl_xor(dd, 32);
    int node = nw + nt * 16 + l15;
    if (quad == 0 && node < N) {
      atomicAdd(&partc[node], c);
      atomicAdd(&parts[node], s);
      atomicAdd(&partd[node], dd);
    }
  }
}

// ---------------- layer-2 attention: 16-lane segment per dst ----------------

__global__ __launch_bounds__(256) void k_attn2s(const float* __restrict__ partc,
                                                const float* __restrict__ parts,
                                                const float* __restrict__ partd,
                                                const int* __restrict__ row_ptr,
                                                const int* __restrict__ csr,
                                                const float* __restrict__ cconst,
                                                float* __restrict__ out, int N) {
  int grp = threadIdx.x >> 4, l = threadIdx.x & 15;
  int d = blockIdx.x * 16 + grp;
  if (d >= N) return;
  int e0 = row_ptr[d], deg = row_ptr[d + 1] - e0;
  float aldd = partd[d];
  float z = 0.f, num = 0.f;
  for (int e = l; e < deg; e += 16) {
    int s = csr[e0 + e];
    float v = __expf(leaky(parts[s] + aldd));
    z += v;
    num += v * partc[s];
  }
#pragma unroll
  for (int off = 8; off; off >>= 1) {
    z += __shfl_xor(z, off);
    num += __shfl_xor(num, off);
  }
  if (l == 0) out[d] = num / (z + 1e-16f) + cconst[0];
}

// ---------------- launch ----------------

extern "C" void kernel_launch(void* const* d_in, const int* in_sizes, int n_in,
                              void* d_out, int out_size, void* d_ws, size_t ws_size,
                              hipStream_t stream) {
  const float* x      = (const float*)d_in[0];
  const int*   ei     = (const int*)d_in[1];
  const float* W1     = (const float*)d_in[2];
  const float* a_src1 = (const float*)d_in[3];
  const float* a_dst1 = (const float*)d_in[4];
  const float* b1     = (const float*)d_in[5];
  const float* W2     = (const float*)d_in[6];
  const float* a_src2 = (const float*)d_in[7];
  const float* a_dst2 = (const float*)d_in[8];
  const float* b2     = (const float*)d_in[9];
  const float* Wc     = (const float*)d_in[10];
  const float* bc     = (const float*)d_in[11];

  int N = in_sizes[0] / EMBED;
  int E = in_sizes[1] / 2;
  int Et = E + N;

  char* ws = (char*)d_ws;
  size_t off = 0;
  auto alloc = [&](size_t bytes) -> void* {
    void* p = ws + off;
    off += (bytes + 255) & ~(size_t)255;
    return p;
  };
  __hip_bfloat16* xaggb = (__hip_bfloat16*)alloc((size_t)N * 2048 * 2 + 65536);
  short* w1t_hi = (short*)alloc((size_t)262144 * 2);
  short* w1t_lo = (short*)alloc((size_t)262144 * 2);
  float* wsAll  = (float*)alloc(4096 * 4);
  float* uvec   = (float*)alloc(6144 * 4);
  float* cconst = (float*)alloc(256);
  float* als1   = (float*)alloc((size_t)N * 16 * 4);
  float* ald1   = (float*)alloc((size_t)N * 16 * 4);
  float* part   = (float*)alloc((size_t)3 * N * 4);
  float* partc  = part;
  float* parts  = part + N;
  float* partd  = part + 2 * N;
  int* deg      = (int*)alloc((size_t)N * 4);
  int* row_ptr  = (int*)alloc((size_t)(N + 1) * 4);
  int* cursor   = (int*)alloc((size_t)N * 4);
  int* csr      = (int*)alloc((size_t)Et * 4);

  // 1: prep (also zeroes deg + part — no memset dispatch needed)
  int nPrepB = 64 + (10496 + 4 * N + 255) / 256;
  k_prep<<<nPrepB, 256, 0, stream>>>(W1, a_src1, a_dst1, W2, a_src2, a_dst2, Wc, b2, bc,
                                     wsAll, uvec, cconst, w1t_hi, w1t_lo, part, deg, N);
  // 2-4: CSR build
  k_hist<<<(Et + 255) / 256, 256, 0, stream>>>(ei, E, N, deg);
  k_scan<<<1, 1024, 0, stream>>>(deg, row_ptr, cursor, N);
  k_scatter<<<(Et + 255) / 256, 256, 0, stream>>>(ei, E, N, cursor, csr);
  // 5: layer-1 logits
  k_al1v2<<<(N * 16 + 255) / 256, 256, 0, stream>>>(x, wsAll, als1, ald1, N);
  // 6: layer-1 attention aggregate
  k_attn1h<<<(N + 1) / 2, 256, 0, stream>>>(x, als1, ald1, row_ptr, csr, xaggb, N);
  // 7: fused projection + elu + u-dots, atomic per-head accumulation
  k_fused<<<dim3((N + 255) / 256, 16), 256, 0, stream>>>(xaggb, w1t_hi, w1t_lo, b1, uvec,
                                                         partc, parts, partd, N);
  // 8: layer-2 attention
  k_attn2s<<<(N + 15) / 16, 256, 0, stream>>>(partc, parts, partd, row_ptr, csr, cconst,
                                              (float*)d_out, N);
}

// Round 2
// 179.475 us; speedup vs baseline: 1.0581x; 1.0222x over previous
//
#include <hip/hip_runtime.h>
#include <hip/hip_bf16.h>

#define EMBED 128
#define HEADS 16
#define NEG 0.2f

typedef __attribute__((ext_vector_type(8))) short short8;
typedef __attribute__((ext_vector_type(4))) float floatx4;

// async global->LDS, 16B per lane; dest must be wave-uniform base + lane*16
#define GLOAD_LDS16(g, l)                                                                  \
  __builtin_amdgcn_global_load_lds((const __attribute__((address_space(1))) unsigned int*)(g), \
                                   (__attribute__((address_space(3))) unsigned int*)(l),       \
                                   16, 0, 0)

static __device__ __forceinline__ float leaky(float x) { return x > 0.f ? x : NEG * x; }

static __device__ __forceinline__ short f2bf_bits(float f) {
  __hip_bfloat16 h = __float2bfloat16(f);
  union { __hip_bfloat16 b; short s; } u;
  u.b = h;
  return u.s;
}

// ---------------- CSR build ----------------

__global__ void k_hist(const int* __restrict__ ei, int E, int N, int* __restrict__ deg) {
  int i = blockIdx.x * blockDim.x + threadIdx.x;
  int Et = E + N;
  if (i >= Et) return;
  int d = (i < E) ? ei[E + i] : (i - E);
  atomicAdd(&deg[d], 1);
}

// single-block shuffle scan over deg -> row_ptr/cursor
__global__ __launch_bounds__(1024) void k_scan(const int* __restrict__ deg,
                                               int* __restrict__ row_ptr,
                                               int* __restrict__ cursor, int N) {
  __shared__ int wsum[16];
  int tid = threadIdx.x;
  int lane = tid & 63, w = tid >> 6;
  int base = 0;
  for (int c0 = 0; c0 < N; c0 += 1024) {
    int i = c0 + tid;
    int v = (i < N) ? deg[i] : 0;
    int s = v;
#pragma unroll
    for (int dd = 1; dd < 64; dd <<= 1) {
      int t = __shfl_up(s, dd);
      if (lane >= dd) s += t;
    }
    if (lane == 63) wsum[w] = s;
    __syncthreads();
    int carry = 0, ctot = 0;
#pragma unroll
    for (int k = 0; k < 16; ++k) {
      int t = wsum[k];
      ctot += t;
      if (k < w) carry += t;
    }
    int excl = base + carry + s - v;
    if (i < N) {
      row_ptr[i] = excl;
      cursor[i] = excl;
    }
    base += ctot;
    __syncthreads();
  }
  if (tid == 0) row_ptr[N] = base;
}

// ---------------- merged: scatter (blocks [0,nScat)) + layer-1 logits (rest) ----------------

__global__ __launch_bounds__(256) void k_scat_al1(const int* __restrict__ ei, int E, int N,
                                                  int* __restrict__ cursor,
                                                  int* __restrict__ csr_src,
                                                  const float* __restrict__ x,
                                                  const float* __restrict__ wsAll,
                                                  float* __restrict__ als,
                                                  float* __restrict__ ald, int nScat) {
  __shared__ float wss[128][16], wsd[128][16];
  if ((int)blockIdx.x < nScat) {
    int i = blockIdx.x * 256 + threadIdx.x;
    int Et = E + N;
    if (i >= Et) return;
    int s = (i < E) ? ei[i] : (i - E);
    int d = (i < E) ? ei[E + i] : (i - E);
    int pos = atomicAdd(&cursor[d], 1);
    csr_src[pos] = s;
    return;
  }
  int tid = threadIdx.x;
  for (int i = tid; i < 2048; i += 256) {
    int h = i >> 7, c = i & 127;
    wss[c][h] = wsAll[i];
    wsd[c][h] = wsAll[2048 + i];
  }
  __syncthreads();
  int gid = ((int)blockIdx.x - nScat) * 256 + tid;
  int n = gid >> 4, h = gid & 15;
  if (n >= N) return;
  const float4* xp = (const float4*)(x + (size_t)n * 128);
  float ps = 0.f, pd = 0.f;
#pragma unroll 8
  for (int c4 = 0; c4 < 32; ++c4) {
    float4 xv = xp[c4];
    int c = c4 * 4;
    ps += xv.x * wss[c][h] + xv.y * wss[c + 1][h] + xv.z * wss[c + 2][h] + xv.w * wss[c + 3][h];
    pd += xv.x * wsd[c][h] + xv.y * wsd[c + 1][h] + xv.z * wsd[c + 2][h] + xv.w * wsd[c + 3][h];
  }
  als[gid] = ps;
  ald[gid] = pd;
}

// ---------------- merged prep: W1^T transpose (blocks 0..63) + w~/u vectors + zeroing ----------------

__global__ __launch_bounds__(256) void k_prep(const float* __restrict__ W1,
                                              const float* __restrict__ a_src1,
                                              const float* __restrict__ a_dst1,
                                              const float* __restrict__ W2,
                                              const float* __restrict__ a_src2,
                                              const float* __restrict__ a_dst2,
                                              const float* __restrict__ Wc,
                                              const float* __restrict__ b2,
                                              const float* __restrict__ bc,
                                              float* __restrict__ wsAll,
                                              float* __restrict__ uvec,
                                              float* __restrict__ cconst,
                                              short* __restrict__ hi,
                                              short* __restrict__ lo,
                                              float* __restrict__ part,
                                              int* __restrict__ deg,
                                              int N) {
  __shared__ float tile[64][65];
  if (blockIdx.x < 64) {
    int b = blockIdx.x;
    int h = b & 15;
    int c0 = ((b >> 4) & 1) * 64;
    int j0 = ((b >> 5) & 1) * 64;
    int t = threadIdx.x;
#pragma unroll
    for (int i = 0; i < 4; ++i) {
      int idx4 = i * 256 + t;
      int c = idx4 >> 4, j4 = idx4 & 15;
      float4 v = *(const float4*)&W1[(size_t)(c0 + c) * 2048 + h * 128 + j0 + j4 * 4];
      tile[c][j4 * 4 + 0] = v.x;
      tile[c][j4 * 4 + 1] = v.y;
      tile[c][j4 * 4 + 2] = v.z;
      tile[c][j4 * 4 + 3] = v.w;
    }
    __syncthreads();
#pragma unroll
    for (int i = 0; i < 4; ++i) {
      int idx = i * 256 + t;
      int j = idx >> 4, c4 = idx & 15;
      unsigned short vh[4], vl[4];
#pragma unroll
      for (int ii = 0; ii < 4; ++ii) {
        float wv = tile[c4 * 4 + ii][j];
        short hb = f2bf_bits(wv);
        float hf = __uint_as_float(((unsigned int)(unsigned short)hb) << 16);
        vh[ii] = (unsigned short)hb;
        vl[ii] = (unsigned short)f2bf_bits(wv - hf);
      }
      size_t o = (size_t)h * 16384 + (size_t)(j0 + j) * 128 + c0 + c4 * 4;
      *(ushort4*)&hi[o] = make_ushort4(vh[0], vh[1], vh[2], vh[3]);
      *(ushort4*)&lo[o] = make_ushort4(vl[0], vl[1], vl[2], vl[3]);
    }
    return;
  }
  int gid = (blockIdx.x - 64) * 256 + threadIdx.x;
  if (gid < 4096) {
    int sel = gid >> 11;
    int id = gid & 2047;
    int h = id >> 7, k = id & 127;
    const float* av = sel ? a_dst1 : a_src1;
    float sum = 0.f;
    const float* wrow = W1 + (size_t)k * 2048 + h * 128;
    const float* arow = av + h * 128;
#pragma unroll 4
    for (int c = 0; c < 128; ++c) sum += wrow[c] * arow[c];
    wsAll[gid] = sum;
  } else if (gid < 10240) {
    int g = gid - 4096;
    int sel = g >> 11;  // 0: Wc, 1: a_src2, 2: a_dst2
    int k = g & 2047;
    const float* v = sel == 0 ? Wc : (sel == 1 ? a_src2 : a_dst2);
    const float* wrow = W2 + (size_t)k * 128;
    float s = 0.f;
#pragma unroll 4
    for (int j = 0; j < 128; ++j) s += wrow[j] * v[j];
    uvec[g] = s;
  } else if (gid == 10240) {
    float s = 0.f;
    for (int j = 0; j < 128; ++j) s += b2[j] * Wc[j];
    *cconst = s + bc[0];
  } else if (gid >= 10496) {
    int z = gid - 10496;
    if (z < 3 * N) part[z] = 0.f;
    else if (z < 4 * N) deg[z - 3 * N] = 0;
  }
}

// ---------------- layer-1 attention: staged CSR in regs + depth-2 software pipeline ----------------

__global__ __launch_bounds__(256) void k_attn1h(const float* __restrict__ x,
                                                const float* __restrict__ als,
                                                const float* __restrict__ ald,
                                                const int* __restrict__ row_ptr,
                                                const int* __restrict__ csr,
                                                __hip_bfloat16* __restrict__ xaggb,
                                                int N) {
  __shared__ float accsh[2][64][37];  // 32 acc + 4 z per lane

  int tid = threadIdx.x;
  int w = tid >> 6, lane = tid & 63;
  int slot = w >> 1, half = w & 1;
  int d = blockIdx.x * 2 + slot;
  bool active = d < N;

  int e0 = 0, deg = 0;
  if (active) {
    e0 = row_ptr[d];
    deg = row_ptr[d + 1] - e0;
  }

  int g = lane >> 4, c8 = lane & 15;
  float4 aldh4 = make_float4(0.f, 0.f, 0.f, 0.f);
  if (active) aldh4 = *(const float4*)&ald[(size_t)d * 16 + g * 4];

  float acc[4][8];
  float zacc[4] = {0.f, 0.f, 0.f, 0.f};
#pragma unroll
  for (int hh = 0; hh < 4; ++hh)
#pragma unroll
    for (int i = 0; i < 8; ++i) acc[hh][i] = 0.f;

  if (active) {
    int sreg = 0;
    if (lane < deg) sreg = csr[e0 + lane];
    const float* xc = x + c8 * 8;

    int e = half;
    bool have = e < deg;
    int sC = 0;
    float4 alC = make_float4(0.f, 0.f, 0.f, 0.f);
    float4 xaC = alC, xbC = alC;
    if (have) {
      sC = (e < 64) ? __shfl(sreg, e) : csr[e0 + e];
      alC = *(const float4*)&als[(size_t)sC * 16 + g * 4];
      const float4* xp = (const float4*)(xc + (size_t)sC * 128);
      xaC = xp[0];
      xbC = xp[1];
    }
    while (have) {
      int e2 = e + 2;
      bool have2 = e2 < deg;
      int sN = 0;
      float4 alN = alC, xaN = xaC, xbN = xbC;
      if (have2) {
        sN = (e2 < 64) ? __shfl(sreg, e2) : csr[e0 + e2];
        alN = *(const float4*)&als[(size_t)sN * 16 + g * 4];
        const float4* xp2 = (const float4*)(xc + (size_t)sN * 128);
        xaN = xp2[0];
        xbN = xp2[1];
      }
      float ev0 = __expf(leaky(alC.x + aldh4.x));
      float ev1 = __expf(leaky(alC.y + aldh4.y));
      float ev2 = __expf(leaky(alC.z + aldh4.z));
      float ev3 = __expf(leaky(alC.w + aldh4.w));
      zacc[0] += ev0; zacc[1] += ev1; zacc[2] += ev2; zacc[3] += ev3;
      acc[0][0] += ev0 * xaC.x; acc[0][1] += ev0 * xaC.y; acc[0][2] += ev0 * xaC.z; acc[0][3] += ev0 * xaC.w;
      acc[0][4] += ev0 * xbC.x; acc[0][5] += ev0 * xbC.y; acc[0][6] += ev0 * xbC.z; acc[0][7] += ev0 * xbC.w;
      acc[1][0] += ev1 * xaC.x; acc[1][1] += ev1 * xaC.y; acc[1][2] += ev1 * xaC.z; acc[1][3] += ev1 * xaC.w;
      acc[1][4] += ev1 * xbC.x; acc[1][5] += ev1 * xbC.y; acc[1][6] += ev1 * xbC.z; acc[1][7] += ev1 * xbC.w;
      acc[2][0] += ev2 * xaC.x; acc[2][1] += ev2 * xaC.y; acc[2][2] += ev2 * xaC.z; acc[2][3] += ev2 * xaC.w;
      acc[2][4] += ev2 * xbC.x; acc[2][5] += ev2 * xbC.y; acc[2][6] += ev2 * xbC.z; acc[2][7] += ev2 * xbC.w;
      acc[3][0] += ev3 * xaC.x; acc[3][1] += ev3 * xaC.y; acc[3][2] += ev3 * xaC.z; acc[3][3] += ev3 * xaC.w;
      acc[3][4] += ev3 * xbC.x; acc[3][5] += ev3 * xbC.y; acc[3][6] += ev3 * xbC.z; acc[3][7] += ev3 * xbC.w;
      e = e2;
      have = have2;
      sC = sN;
      alC = alN;
      xaC = xaN;
      xbC = xbN;
    }
  }

  if (half == 1) {
#pragma unroll
    for (int hh = 0; hh < 4; ++hh) {
#pragma unroll
      for (int i = 0; i < 8; ++i)
        accsh[slot][lane][hh * 8 + i] = acc[hh][i];
      accsh[slot][lane][32 + hh] = zacc[hh];
    }
  }
  __syncthreads();
  if (half == 0 && active) {
#pragma unroll
    for (int hh = 0; hh < 4; ++hh) {
      int h = g * 4 + hh;
      float z = zacc[hh] + accsh[slot][lane][32 + hh];
      float iz = 1.f / (z + 1e-16f);
      __hip_bfloat16 t[8];
#pragma unroll
      for (int i = 0; i < 8; ++i) {
        float v = (acc[hh][i] + accsh[slot][lane][hh * 8 + i]) * iz;
        t[i] = __float2bfloat16(v);
      }
      *(uint4*)(xaggb + (size_t)h * N * 128 + (size_t)d * 128 + c8 * 8) = *(uint4*)t;
    }
  }
}

// ---------------- fused: Bh+Bl staged via global_load_lds (pre-swizzled source) ----------------

__global__ __launch_bounds__(256, 2) void k_fused(const __hip_bfloat16* __restrict__ xaggb,
                                                  const short* __restrict__ w1t_hi,
                                                  const short* __restrict__ w1t_lo,
                                                  const float* __restrict__ b1,
                                                  const float* __restrict__ uvec,
                                                  float2* __restrict__ part2,
                                                  float* __restrict__ partd,
                                                  int N) {
  __shared__ float sh[512];
  __shared__ __align__(16) char Bh[32768];
  __shared__ __align__(16) char Bl[32768];
  int tid = threadIdx.x;
  int h = blockIdx.y;
  int n0 = blockIdx.x * 256;

  // async weight staging: linear LDS dest (base + lane*16), XOR-swizzled global source.
  // LDS content is byte-identical to the old VGPR-roundtrip swizzled staging.
  const char* gbh = (const char*)(w1t_hi + (size_t)h * 16384);
  const char* gbl = (const char*)(w1t_lo + (size_t)h * 16384);
#pragma unroll
  for (int i = 0; i < 8; ++i) {
    int ci = i * 256 + tid;
    int row4 = (ci >> 4) & 15;
    int srcoff = ((ci & ~15) | ((ci & 15) ^ row4)) << 4;
    GLOAD_LDS16(gbh + srcoff, Bh + ci * 16);
    GLOAD_LDS16(gbl + srcoff, Bl + ci * 16);
  }

  for (int i = tid; i < 512; i += 256) {
    int arr = i >> 7, jj = i & 127;
    sh[i] = (arr == 0) ? b1[h * 128 + jj] : uvec[(arr - 1) * 2048 + h * 128 + jj];
  }

  int w = tid >> 6, lane = tid & 63;
  int quad = lane >> 4, l15 = lane & 15;
  int nw = n0 + w * 64;

  const char* abase = (const char*)xaggb + (size_t)h * N * 256;
  short8 a[4][4];
#pragma unroll
  for (int nt = 0; nt < 4; ++nt) {
    int node = nw + nt * 16 + l15;
    if (node >= N) node = N - 1;
    const char* rowp = abase + (size_t)node * 256 + quad * 16;
#pragma unroll
    for (int ks = 0; ks < 4; ++ks)
      a[nt][ks] = *(const short8*)(rowp + ks * 64);
  }
  __syncthreads();

  floatx4 acc[4][8];
#pragma unroll
  for (int jt = 0; jt < 8; ++jt) {
    floatx4 bb = *(const floatx4*)&sh[jt * 16 + quad * 4];
#pragma unroll
    for (int nt = 0; nt < 4; ++nt) acc[nt][jt] = bb;
  }

  __builtin_amdgcn_s_setprio(1);
  for (int ks = 0; ks < 4; ++ks) {
    int xo = (((ks * 4 + quad) ^ l15) << 4);
#pragma unroll
    for (int jt = 0; jt < 8; ++jt) {
      int po = (jt * 16 + l15) * 256 + xo;
      short8 wh = *(const short8*)(Bh + po);
      short8 wl = *(const short8*)(Bl + po);
#pragma unroll
      for (int nt = 0; nt < 4; ++nt) {
        acc[nt][jt] = __builtin_amdgcn_mfma_f32_16x16x32_bf16(wh, a[nt][ks], acc[nt][jt], 0, 0, 0);
        acc[nt][jt] = __builtin_amdgcn_mfma_f32_16x16x32_bf16(wl, a[nt][ks], acc[nt][jt], 0, 0, 0);
      }
    }
  }
  __builtin_amdgcn_s_setprio(0);

  float pc[4] = {0.f, 0.f, 0.f, 0.f};
  float ps[4] = {0.f, 0.f, 0.f, 0.f};
  float pd[4] = {0.f, 0.f, 0.f, 0.f};
#pragma unroll
  for (int jt = 0; jt < 8; ++jt) {
    floatx4 uc = *(const floatx4*)&sh[128 + jt * 16 + quad * 4];
    floatx4 us = *(const floatx4*)&sh[256 + jt * 16 + quad * 4];
    floatx4 ud = *(const floatx4*)&sh[384 + jt * 16 + quad * 4];
#pragma unroll
    for (int nt = 0; nt < 4; ++nt) {
#pragma unroll
      for (int r = 0; r < 4; ++r) {
        float v = acc[nt][jt][r];
        float e = v > 0.f ? v : (__expf(v) - 1.f);
        pc[nt] += e * uc[r];
        ps[nt] += e * us[r];
        pd[nt] += e * ud[r];
      }
    }
  }
#pragma unroll
  for (int nt = 0; nt < 4; ++nt) {
    float c = pc[nt], s = ps[nt], dd = pd[nt];
    c += __shfl_xor(c, 16); c += __shfl_xor(c, 32);
    s += __shfl_xor(s, 16); s += __shfl_xor(s, 32);
    dd += __shfl_xor(dd, 16); dd += __shfl_xor(dd, 32);
    int node = nw + nt * 16 + l15;
    if (quad == 0 && node < N) {
      atomicAdd(&part2[node].x, s);
      atomicAdd(&part2[node].y, c);
      atomicAdd(&partd[node], dd);
    }
  }
}

// ---------------- layer-2 attention: 16-lane segment per dst, float2 gather ----------------

__global__ __launch_bounds__(256) void k_attn2s(const float2* __restrict__ part2,
                                                const float* __restrict__ partd,
                                                const int* __restrict__ row_ptr,
                                                const int* __restrict__ csr,
                                                const float* __restrict__ cconst,
                                                float* __restrict__ out, int N) {
  int grp = threadIdx.x >> 4, l = threadIdx.x & 15;
  int d = blockIdx.x * 16 + grp;
  if (d >= N) return;
  int e0 = row_ptr[d], deg = row_ptr[d + 1] - e0;
  float aldd = partd[d];
  float z = 0.f, num = 0.f;
  for (int e = l; e < deg; e += 16) {
    int s = csr[e0 + e];
    float2 v2 = part2[s];
    float v = __expf(leaky(v2.x + aldd));
    z += v;
    num += v * v2.y;
  }
#pragma unroll
  for (int off = 8; off; off >>= 1) {
    z += __shfl_xor(z, off);
    num += __shfl_xor(num, off);
  }
  if (l == 0) out[d] = num / (z + 1e-16f) + cconst[0];
}

// ---------------- launch ----------------

extern "C" void kernel_launch(void* const* d_in, const int* in_sizes, int n_in,
                              void* d_out, int out_size, void* d_ws, size_t ws_size,
                              hipStream_t stream) {
  const float* x      = (const float*)d_in[0];
  const int*   ei     = (const int*)d_in[1];
  const float* W1     = (const float*)d_in[2];
  const float* a_src1 = (const float*)d_in[3];
  const float* a_dst1 = (const float*)d_in[4];
  const float* b1     = (const float*)d_in[5];
  const float* W2     = (const float*)d_in[6];
  const float* a_src2 = (const float*)d_in[7];
  const float* a_dst2 = (const float*)d_in[8];
  const float* b2     = (const float*)d_in[9];
  const float* Wc     = (const float*)d_in[10];
  const float* bc     = (const float*)d_in[11];

  int N = in_sizes[0] / EMBED;
  int E = in_sizes[1] / 2;
  int Et = E + N;

  char* ws = (char*)d_ws;
  size_t off = 0;
  auto alloc = [&](size_t bytes) -> void* {
    void* p = ws + off;
    off += (bytes + 255) & ~(size_t)255;
    return p;
  };
  __hip_bfloat16* xaggb = (__hip_bfloat16*)alloc((size_t)N * 2048 * 2 + 65536);
  short* w1t_hi = (short*)alloc((size_t)262144 * 2);
  short* w1t_lo = (short*)alloc((size_t)262144 * 2);
  float* wsAll  = (float*)alloc(4096 * 4);
  float* uvec   = (float*)alloc(6144 * 4);
  float* cconst = (float*)alloc(256);
  float* als1   = (float*)alloc((size_t)N * 16 * 4);
  float* ald1   = (float*)alloc((size_t)N * 16 * 4);
  float* part   = (float*)alloc((size_t)3 * N * 4);   // [part2 (2N) | partd (N)]
  float2* part2 = (float2*)part;
  float* partd  = part + 2 * N;
  int* deg      = (int*)alloc((size_t)N * 4);
  int* row_ptr  = (int*)alloc((size_t)(N + 1) * 4);
  int* cursor   = (int*)alloc((size_t)N * 4);
  int* csr      = (int*)alloc((size_t)Et * 4);

  int nScat = (Et + 255) / 256;
  int nAl1  = (N * 16 + 255) / 256;

  // 1: prep (also zeroes deg + part)
  int nPrepB = 64 + (10496 + 4 * N + 255) / 256;
  k_prep<<<nPrepB, 256, 0, stream>>>(W1, a_src1, a_dst1, W2, a_src2, a_dst2, Wc, b2, bc,
                                     wsAll, uvec, cconst, w1t_hi, w1t_lo, part, deg, N);
  // 2-3: CSR histogram + scan
  k_hist<<<(Et + 255) / 256, 256, 0, stream>>>(ei, E, N, deg);
  k_scan<<<1, 1024, 0, stream>>>(deg, row_ptr, cursor, N);
  // 4: scatter + layer-1 logits (merged)
  k_scat_al1<<<nScat + nAl1, 256, 0, stream>>>(ei, E, N, cursor, csr, x, wsAll, als1, ald1,
                                               nScat);
  // 5: layer-1 attention aggregate
  k_attn1h<<<(N + 1) / 2, 256, 0, stream>>>(x, als1, ald1, row_ptr, csr, xaggb, N);
  // 6: fused projection + elu + u-dots
  k_fused<<<dim3((N + 255) / 256, 16), 256, 0, stream>>>(xaggb, w1t_hi, w1t_lo, b1, uvec,
                                                         part2, partd, N);
  // 7: layer-2 attention
  k_attn2s<<<(N + 15) / 16, 256, 0, stream>>>(part2, partd, row_ptr, csr, cconst,
                                              (float*)d_out, N);
}